// Round 13
// baseline (424.320 us; speedup 1.0000x reference)
//
#include <hip/hip_runtime.h>
#include <math.h>

#define EPS 1e-5f
#define MODW 132   // compact mod row: [0..2]=scales (+1 pad), [4..131]=shift[0..127]

#define RG 128                 // rowgroups (B/8)
#define S1_BLKS (RG * 8)       // 1024
#define S2_BLKS (RG * 8)       // 1024
#define S3_BLKS (RG * 3)       // 384
#define MLP_BLKS (S1_BLKS + S2_BLKS + S3_BLKS)   // 2432

__device__ __forceinline__ float silu_f(float x) {
    return x / (1.0f + expf(-x));
}

// ---- one MLP stage slice on 256 threads: 8 rows x 64 cols, split-k 4 ----
// (verbatim from R10 -- correctness-proven). k-loop in chunks of 16: 16
// independent scalar w loads per batch, then 4x[8 LDS float4 broadcasts +
// 32 FMAs]. Split-k partials reduced via LDS.
template <int K, int OUTC, bool EMB, bool SILU, bool COLMAP>
__device__ __forceinline__ void stage256(
    const float* __restrict__ src,   // [*][K] rows (or t[] if EMB)
    const float* __restrict__ w,     // [K][NCW]
    int NCW,
    const float* __restrict__ bias,  // [NCW]
    float* __restrict__ dst, int dstride,
    int row0, int col0,
    float* s_in, float* s_acc, int tid)
{
    if constexpr (EMB) {
        const float lm = 9.210340371976184f;   // ln(10000)
        for (int idx = tid; idx < 8 * K; idx += 256) {
            int r = idx / K, j = idx - r * K;
            int h = j & 127;
            float freq = expf(-lm * (float)h * (1.0f / 128.0f));
            float arg = src[row0 + r] * freq;
            s_in[r * K + j] = (j < 128) ? cosf(arg) : sinf(arg);
        }
    } else {
        for (int idx = tid; idx < 8 * (K / 4); idx += 256) {
            int r = idx / (K / 4), k4 = idx - r * (K / 4);
            *(float4*)&s_in[r * K + k4 * 4] =
                *(const float4*)(src + (size_t)(row0 + r) * K + k4 * 4);
        }
    }
    __syncthreads();

    int c  = tid & 63;
    int ks = tid >> 6;                 // wave-uniform k-slice (0..3)
    constexpr int KC = K / 4;
    int oc = col0 + c;
    int occ = (oc < OUTC) ? oc : (OUTC - 1);                // clamp (never stored)
    int wcol = COLMAP ? ((occ < 4) ? occ : (220 + occ)) : occ;
    const float* wp = w + wcol;

    float acc[8] = {0, 0, 0, 0, 0, 0, 0, 0};
    int kbeg = ks * KC;
#pragma unroll 1
    for (int k0 = kbeg; k0 < kbeg + KC; k0 += 16) {
        float wv[16];
#pragma unroll
        for (int u = 0; u < 16; ++u) wv[u] = wp[(size_t)(k0 + u) * NCW];
#pragma unroll
        for (int q = 0; q < 4; ++q) {
            float4 sa[8];
#pragma unroll
            for (int r = 0; r < 8; ++r) sa[r] = *(const float4*)&s_in[r * K + k0 + 4 * q];
#pragma unroll
            for (int u = 0; u < 4; ++u)
#pragma unroll
                for (int r = 0; r < 8; ++r)
                    acc[r] += ((const float*)&sa[r])[u] * wv[4 * q + u];
        }
    }

#pragma unroll
    for (int r = 0; r < 8; ++r) s_acc[(ks * 8 + r) * 64 + c] = acc[r];
    __syncthreads();

    for (int o = tid; o < 512; o += 256) {
        int r = o >> 6, cc = o & 63;
        int jo = col0 + cc;
        if (jo < OUTC) {
            float v = s_acc[(0 * 8 + r) * 64 + cc] + s_acc[(1 * 8 + r) * 64 + cc]
                    + s_acc[(2 * 8 + r) * 64 + cc] + s_acc[(3 * 8 + r) * 64 + cc];
            int wc = COLMAP ? ((jo < 4) ? jo : (220 + jo)) : jo;
            v += bias[wc];
            if constexpr (SILU) v = silu_f(v);
            dst[(size_t)(row0 + r) * dstride + jo] = v;
        }
    }
}

__device__ __forceinline__ void flag_release(int* f, int tid) {
    __threadfence();
    __syncthreads();
    if (tid == 0) __hip_atomic_fetch_add(f, 1, __ATOMIC_RELEASE, __HIP_MEMORY_SCOPE_AGENT);
}

__device__ __forceinline__ void flag_acquire(const int* f, int target, int tid) {
    if (tid == 0) {
        while (__hip_atomic_load(f, __ATOMIC_ACQUIRE, __HIP_MEMORY_SCOPE_AGENT) < target)
            __builtin_amdgcn_s_sleep(8);
    }
    __syncthreads();
    __threadfence();
}

// Fused MLP with flag dataflow among MLP blocks ONLY (no node-block spinning):
//   bid <  1024 : stage1  (emb -> silu(emb@w1+b1)), release flag1[g]
//   bid <  2048 : stage2  (silu(h1@w2+b2)), acquire flag1[g]==8, release flag2[g]
//   bid <  2432 : stage3  (h2@wm+bm, pruned 132 cols), acquire flag2[g]==8
// In-order dispatch: producers (lower bids) always placed first -> no deadlock.
__global__ __launch_bounds__(256) void k_mlp(
    const float* __restrict__ t,
    const float* __restrict__ w1, const float* __restrict__ b1,
    const float* __restrict__ w2, const float* __restrict__ b2,
    const float* __restrict__ wm, const float* __restrict__ bm,
    int* __restrict__ flags,      // [0..127]=f1, [128..255]=f2
    float* __restrict__ h1, float* __restrict__ h2, float* __restrict__ mb)
{
    __shared__ __align__(16) float s_in[8 * 512];     // 16 KB
    __shared__ __align__(16) float s_acc[4 * 8 * 64]; // 8 KB
    int bid = blockIdx.x;
    int tid = threadIdx.x;

    if (bid < S1_BLKS) {
        int g = bid >> 3, cg = bid & 7;
        stage256<256, 512, true, true, false>(t, w1, 512, b1, h1, 512,
                                              g * 8, cg * 64, s_in, s_acc, tid);
        flag_release(&flags[g], tid);
        return;
    }
    if (bid < S1_BLKS + S2_BLKS) {
        int lb = bid - S1_BLKS;
        int g = lb >> 3, cg = lb & 7;
        flag_acquire(&flags[g], 8, tid);
        stage256<512, 512, false, true, false>(h1, w2, 512, b2, h2, 512,
                                               g * 8, cg * 64, s_in, s_acc, tid);
        flag_release(&flags[128 + g], tid);
        return;
    }
    {
        int lb = bid - (S1_BLKS + S2_BLKS);
        int g = lb / 3, cg = lb - g * 3;
        flag_acquire(&flags[128 + g], 8, tid);
        stage256<512, MODW, false, false, true>(h2, wm, 352, bm, mb, MODW,
                                                g * 8, cg * 64, s_in, s_acc, tid);
    }
}

// One wave (64 lanes) per node. Row = 480 f32 = 120 float4.
// float4 idx:  0..31 -> seg0 (layernorm, floats 0..127)
//             32..79 -> seg1 (floats 128..319, 192 elems)
//             80..119-> seg2 (floats 320..479, 160 elems)
// mod row is compact MODW=132: [0..2] scales, [4+i] = shift[i] (i<128).
__global__ __launch_bounds__(256) void k_main(const float* __restrict__ x,
                                              const int* __restrict__ batch,
                                              const float* __restrict__ mod,
                                              float* __restrict__ out, int N) {
    int node = blockIdx.x * 4 + (threadIdx.x >> 6);
    if (node >= N) return;
    int lane = threadIdx.x & 63;

    const float4* rp = (const float4*)(x + (size_t)node * 480);
    float4 a = rp[lane];                         // f4 idx lane (0..63)
    float4 c = make_float4(0.f, 0.f, 0.f, 0.f);
    if (lane < 56) c = rp[64 + lane];            // f4 idx 64..119

    // hoist the mod gather: issue batch[node] + mod-row loads before the
    // shuffle reduce so their latency overlaps the reduction chain
    int b = batch[node];
    const float* mrow = mod + (size_t)b * MODW;
    float4 m4 = *(const float4*)mrow;            // scales 0..2 (+pad)
    float4 sh = make_float4(0.f, 0.f, 0.f, 0.f);
    if (lane < 32) sh = *(const float4*)(mrow + 4 + 4 * lane);   // shifts

    float s0 = 0.f, q0 = 0.f, q1 = 0.f, q2 = 0.f;
    float da = a.x * a.x + a.y * a.y + a.z * a.z + a.w * a.w;
    if (lane < 32) { s0 = a.x + a.y + a.z + a.w; q0 = da; }
    else           { q1 = da; }
    float dc = c.x * c.x + c.y * c.y + c.z * c.z + c.w * c.w;
    if (lane < 16)      q1 += dc;
    else if (lane < 56) q2 = dc;

#pragma unroll
    for (int m = 1; m < 64; m <<= 1) {
        s0 += __shfl_xor(s0, m, 64);
        q0 += __shfl_xor(q0, m, 64);
        q1 += __shfl_xor(q1, m, 64);
        q2 += __shfl_xor(q2, m, 64);
    }

    float mean = s0 * (1.0f / 128.0f);
    float var  = q0 * (1.0f / 128.0f) - mean * mean;
    float r0 = rsqrtf(var + EPS) * (1.0f + m4.x);
    float r1 = rsqrtf(q1 * (1.0f / 192.0f) + EPS) * (1.0f + m4.y);
    float r2 = rsqrtf(q2 * (1.0f / 160.0f) + EPS) * (1.0f + m4.z);

    float4* op = (float4*)(out + (size_t)node * 480);
    float4 o;
    if (lane < 32) {
        o.x = (a.x - mean) * r0 + sh.x;
        o.y = (a.y - mean) * r0 + sh.y;
        o.z = (a.z - mean) * r0 + sh.z;
        o.w = (a.w - mean) * r0 + sh.w;
    } else {
        o.x = a.x * r1; o.y = a.y * r1; o.z = a.z * r1; o.w = a.w * r1;
    }
    op[lane] = o;
    if (lane < 56) {
        float rr = (lane < 16) ? r1 : r2;
        float4 o2;
        o2.x = c.x * rr; o2.y = c.y * rr; o2.z = c.z * rr; o2.w = c.w * rr;
        op[64 + lane] = o2;
    }
}

extern "C" void kernel_launch(void* const* d_in, const int* in_sizes, int n_in,
                              void* d_out, int out_size, void* d_ws, size_t ws_size,
                              hipStream_t stream) {
    const float* node_input = (const float*)d_in[0];
    const float* t          = (const float*)d_in[1];
    const int*   batch      = (const int*)d_in[2];
    const float* w1         = (const float*)d_in[3];
    const float* b1         = (const float*)d_in[4];
    const float* w2         = (const float*)d_in[5];
    const float* b2         = (const float*)d_in[6];
    const float* wm         = (const float*)d_in[7];
    const float* bm         = (const float*)d_in[8];
    float* out = (float*)d_out;

    int N = in_sizes[0] / 480;   // 100000
    // B = 1024 (RG=128 rowgroups hard-coded)

    float* ws = (float*)d_ws;
    int*   flags = (int*)ws;                       // 256 ints (pad to 1024 floats)
    float* h1 = ws + 1024;                         // 1024*512
    float* h2 = h1 + (size_t)1024 * 512;           // 1024*512
    float* mb = h2 + (size_t)1024 * 512;           // 1024*132

    hipMemsetAsync(flags, 0, 4096, stream);

    k_mlp<<<MLP_BLKS, 256, 0, stream>>>(t, w1, b1, w2, b2, wm, bm,
                                        flags, h1, h2, mb);
    k_main<<<(N + 3) / 4, 256, 0, stream>>>(node_input, batch, mb, out, N);
}

// Round 15
// 130.923 us; speedup vs baseline: 3.2410x; 3.2410x over previous
//
#include <hip/hip_runtime.h>
#include <math.h>

#define EPS 1e-5f
#define MODW 132   // compact mod row: [0..2]=scales (+1 pad), [4..131]=shift[0..127]
#define R 4        // batch rows per block

__device__ __forceinline__ float silu_f(float x) {
    return x / (1.0f + expf(-x));
}

// One full-width MLP stage inside a block: s_out[R][512] = act(s_in[R][K] @ w + b).
// 512 threads = 128 colgroups (4 cols, float4 w loads) x 4 k-slices.
// Per 8k-chunk: 8 independent float4 w loads + 8 LDS float4 broadcasts +
// 128 v_fma (256 cy issue) -> latency covered by FMA issue. Split-k partials
// reduced via s_acc (32 KB). Two barriers per stage.
template <int K, int SSTRIDE, bool SILU>
__device__ __forceinline__ void stage_f(const float* s_in,               // [R][SSTRIDE]
                                        const float* __restrict__ w,     // [K][512]
                                        const float* __restrict__ bias,  // [512]
                                        float* s_out,                    // [R][512]
                                        float* s_acc, int tid)
{
    int cg = tid >> 2;           // 0..127 colgroup
    int ks = tid & 3;            // k-slice
    int j0 = cg * 4;
    const float* wp = w + j0;
    constexpr int KC = K / 4;
    int kbeg = ks * KC;

    float4 acc[R];
#pragma unroll
    for (int r = 0; r < R; ++r) acc[r] = make_float4(0.f, 0.f, 0.f, 0.f);

#pragma unroll 1
    for (int k0 = kbeg; k0 < kbeg + KC; k0 += 8) {
        float4 wv[8];
#pragma unroll
        for (int u = 0; u < 8; ++u) wv[u] = *(const float4*)(wp + (size_t)(k0 + u) * 512);
        float4 sa[R][2];
#pragma unroll
        for (int r = 0; r < R; ++r) {
            sa[r][0] = *(const float4*)&s_in[r * SSTRIDE + k0];
            sa[r][1] = *(const float4*)&s_in[r * SSTRIDE + k0 + 4];
        }
#pragma unroll
        for (int u = 0; u < 8; ++u) {
#pragma unroll
            for (int r = 0; r < R; ++r) {
                float s = ((const float*)&sa[r][u >> 2])[u & 3];
                acc[r].x += s * wv[u].x; acc[r].y += s * wv[u].y;
                acc[r].z += s * wv[u].z; acc[r].w += s * wv[u].w;
            }
        }
    }

#pragma unroll
    for (int r = 0; r < R; ++r)
        *(float4*)&s_acc[(size_t)(ks * R + r) * 512 + j0] = acc[r];
    __syncthreads();

    // reduce 4 slices: 512 threads x 4 cols = R*512 outputs
    {
        int r  = tid >> 7;             // 0..3
        int c4 = (tid & 127) * 4;
        float4 v0 = *(const float4*)&s_acc[(size_t)(0 * R + r) * 512 + c4];
        float4 v1 = *(const float4*)&s_acc[(size_t)(1 * R + r) * 512 + c4];
        float4 v2 = *(const float4*)&s_acc[(size_t)(2 * R + r) * 512 + c4];
        float4 v3 = *(const float4*)&s_acc[(size_t)(3 * R + r) * 512 + c4];
        float4 bv = *(const float4*)(bias + c4);
        float4 o;
        o.x = v0.x + v1.x + v2.x + v3.x + bv.x;
        o.y = v0.y + v1.y + v2.y + v3.y + bv.y;
        o.z = v0.z + v1.z + v2.z + v3.z + bv.z;
        o.w = v0.w + v1.w + v2.w + v3.w + bv.w;
        if (SILU) { o.x = silu_f(o.x); o.y = silu_f(o.y); o.z = silu_f(o.z); o.w = silu_f(o.w); }
        *(float4*)&s_out[r * 512 + c4] = o;
    }
    __syncthreads();
}

// One dispatch, zero cross-block deps: block = 4 batch rows through all stages.
// emb(trig) -> silu(@w1+b1) -> silu(@w2+b2) -> pruned(@wm+bm) -> mb[4][132]
__global__ __launch_bounds__(512) void k_mlp(
    const float* __restrict__ t,
    const float* __restrict__ w1, const float* __restrict__ b1,
    const float* __restrict__ w2, const float* __restrict__ b2,
    const float* __restrict__ wm, const float* __restrict__ bm,
    float* __restrict__ mb)
{
    __shared__ __align__(16) float s_a[R * 512];       // 8 KB (emb stride 256, later h2)
    __shared__ __align__(16) float s_b[R * 512];       // 8 KB (h1)
    __shared__ __align__(16) float s_acc[4 * R * 512]; // 32 KB
    int tid = threadIdx.x;
    int row0 = blockIdx.x * R;

    // timestep embedding into s_a (stride 256): 2 elems/thread
    const float lm = 9.210340371976184f;   // ln(10000)
    for (int idx = tid; idx < R * 256; idx += 512) {
        int r = idx >> 8, j = idx & 255;
        int h = j & 127;
        float freq = expf(-lm * (float)h * (1.0f / 128.0f));
        float arg = t[row0 + r] * freq;
        s_a[r * 256 + j] = (j < 128) ? cosf(arg) : sinf(arg);
    }
    __syncthreads();

    // stage 1: emb(K=256) @ w1 -> silu -> s_b
    stage_f<256, 256, true>(s_a, w1, b1, s_b, s_acc, tid);
    // stage 2: s_b(K=512) @ w2 -> silu (folded trailing silu) -> s_a
    stage_f<512, 512, true>(s_b, w2, b2, s_a, s_acc, tid);

    // stage 3 (pruned): s_a(K=512) @ wm cols {0..3} U [224,352) -> mb[4][132]
    // 64 colgroups x 8 k-slices; colgroups 0..32 active (33*4=132 cols).
    {
        float* s_acc3 = s_acc;     // [8][R][136] = 17.4 KB, aliases s_acc
        int cg = tid >> 3;         // 0..63
        int ks = tid & 7;          // 0..7
        if (cg < 33) {
            int wbase = (cg == 0) ? 0 : (220 + 4 * cg);   // float4-aligned
            const float* wp = wm + wbase;
            constexpr int KC = 64;
            int kbeg = ks * KC;
            float4 acc = make_float4(0.f, 0.f, 0.f, 0.f);
#pragma unroll 1
            for (int k0 = kbeg; k0 < kbeg + KC; k0 += 8) {
                float4 wv[8];
#pragma unroll
                for (int u = 0; u < 8; ++u) wv[u] = *(const float4*)(wp + (size_t)(k0 + u) * 352);
#pragma unroll
                for (int r = 0; r < R; ++r) {
                    float4 sa0 = *(const float4*)&s_a[r * 512 + k0];
                    float4 sa1 = *(const float4*)&s_a[r * 512 + k0 + 4];
                    // accumulate row r's contribution? NO -- acc is per (cg,ks) col-vec
                }
                // (restructured below)
                (void)wv;
            }
            (void)acc;
        }
    }
    // --- stage 3 done properly: each thread owns acc[R] for its 4 cols ---
    {
        float* s_acc3 = s_acc;     // [8][R][136]
        int cg = tid >> 3;         // 0..63
        int ks = tid & 7;
        if (cg < 33) {
            int wbase = (cg == 0) ? 0 : (220 + 4 * cg);
            const float* wp = wm + wbase;
            constexpr int KC = 64;
            int kbeg = ks * KC;
            float4 acc[R];
#pragma unroll
            for (int r = 0; r < R; ++r) acc[r] = make_float4(0.f, 0.f, 0.f, 0.f);
#pragma unroll 1
            for (int k0 = kbeg; k0 < kbeg + KC; k0 += 8) {
                float4 wv[8];
#pragma unroll
                for (int u = 0; u < 8; ++u) wv[u] = *(const float4*)(wp + (size_t)(k0 + u) * 352);
                float4 sa[R][2];
#pragma unroll
                for (int r = 0; r < R; ++r) {
                    sa[r][0] = *(const float4*)&s_a[r * 512 + k0];
                    sa[r][1] = *(const float4*)&s_a[r * 512 + k0 + 4];
                }
#pragma unroll
                for (int u = 0; u < 8; ++u) {
#pragma unroll
                    for (int r = 0; r < R; ++r) {
                        float s = ((const float*)&sa[r][u >> 2])[u & 3];
                        acc[r].x += s * wv[u].x; acc[r].y += s * wv[u].y;
                        acc[r].z += s * wv[u].z; acc[r].w += s * wv[u].w;
                    }
                }
            }
#pragma unroll
            for (int r = 0; r < R; ++r)
                *(float4*)&s_acc3[(size_t)(ks * R + r) * 136 + 4 * cg] = acc[r];
        }
        __syncthreads();

        // reduce 8 slices: R*132 = 528 outputs, threads 0..527
        if (tid < R * 132) {
            int r = tid / 132, c = tid - r * 132;
            float v = 0.f;
#pragma unroll
            for (int s = 0; s < 8; ++s) v += s_acc3[(size_t)(s * R + r) * 136 + c];
            v += bm[(c < 4) ? c : (220 + c)];
            mb[(size_t)(row0 + r) * MODW + c] = v;
        }
    }
}

// One wave (64 lanes) per node. Row = 480 f32 = 120 float4.
// f4 idx: 0..31 seg0 (LN, floats 0..127); 32..79 seg1 (128..319); 80..119 seg2 (320..479)
// mod row compact MODW=132: [0..2] scales, [4+i] = shift[i].
__global__ __launch_bounds__(256) void k_main(const float* __restrict__ x,
                                              const int* __restrict__ batch,
                                              const float* __restrict__ mod,
                                              float* __restrict__ out, int N) {
    int node = blockIdx.x * 4 + (threadIdx.x >> 6);
    if (node >= N) return;
    int lane = threadIdx.x & 63;

    const float4* rp = (const float4*)(x + (size_t)node * 480);
    float4 a = rp[lane];
    float4 c = make_float4(0.f, 0.f, 0.f, 0.f);
    if (lane < 56) c = rp[64 + lane];

    // hoisted mod gather overlaps the shuffle reduce
    int b = batch[node];
    const float* mrow = mod + (size_t)b * MODW;
    float4 m4 = *(const float4*)mrow;
    float4 sh = make_float4(0.f, 0.f, 0.f, 0.f);
    if (lane < 32) sh = *(const float4*)(mrow + 4 + 4 * lane);

    float s0 = 0.f, q0 = 0.f, q1 = 0.f, q2 = 0.f;
    float da = a.x * a.x + a.y * a.y + a.z * a.z + a.w * a.w;
    if (lane < 32) { s0 = a.x + a.y + a.z + a.w; q0 = da; }
    else           { q1 = da; }
    float dc = c.x * c.x + c.y * c.y + c.z * c.z + c.w * c.w;
    if (lane < 16)      q1 += dc;
    else if (lane < 56) q2 = dc;

#pragma unroll
    for (int m = 1; m < 64; m <<= 1) {
        s0 += __shfl_xor(s0, m, 64);
        q0 += __shfl_xor(q0, m, 64);
        q1 += __shfl_xor(q1, m, 64);
        q2 += __shfl_xor(q2, m, 64);
    }

    float mean = s0 * (1.0f / 128.0f);
    float var  = q0 * (1.0f / 128.0f) - mean * mean;
    float r0 = rsqrtf(var + EPS) * (1.0f + m4.x);
    float r1 = rsqrtf(q1 * (1.0f / 192.0f) + EPS) * (1.0f + m4.y);
    float r2 = rsqrtf(q2 * (1.0f / 160.0f) + EPS) * (1.0f + m4.z);

    float4* op = (float4*)(out + (size_t)node * 480);
    float4 o;
    if (lane < 32) {
        o.x = (a.x - mean) * r0 + sh.x;
        o.y = (a.y - mean) * r0 + sh.y;
        o.z = (a.z - mean) * r0 + sh.z;
        o.w = (a.w - mean) * r0 + sh.w;
    } else {
        o.x = a.x * r1; o.y = a.y * r1; o.z = a.z * r1; o.w = a.w * r1;
    }
    op[lane] = o;
    if (lane < 56) {
        float rr = (lane < 16) ? r1 : r2;
        float4 o2;
        o2.x = c.x * rr; o2.y = c.y * rr; o2.z = c.z * rr; o2.w = c.w * rr;
        op[64 + lane] = o2;
    }
}

extern "C" void kernel_launch(void* const* d_in, const int* in_sizes, int n_in,
                              void* d_out, int out_size, void* d_ws, size_t ws_size,
                              hipStream_t stream) {
    const float* node_input = (const float*)d_in[0];
    const float* t          = (const float*)d_in[1];
    const int*   batch      = (const int*)d_in[2];
    const float* w1         = (const float*)d_in[3];
    const float* b1         = (const float*)d_in[4];
    const float* w2         = (const float*)d_in[5];
    const float* b2         = (const float*)d_in[6];
    const float* wm         = (const float*)d_in[7];
    const float* bm         = (const float*)d_in[8];
    float* out = (float*)d_out;

    int N = in_sizes[0] / 480;   // 100000
    int B = in_sizes[1];         // 1024

    float* mb = (float*)d_ws;    // B*132 compact mod

    k_mlp<<<B / R, 512, 0, stream>>>(t, w1, b1, w2, b2, wm, bm, mb);
    k_main<<<(N + 3) / 4, 256, 0, stream>>>(node_input, batch, mb, out, N);
}

// Round 16
// 116.610 us; speedup vs baseline: 3.6388x; 1.1227x over previous
//
#include <hip/hip_runtime.h>
#include <math.h>

#define EPS 1e-5f
#define MODW 132   // compact mod row: [0..3]=scale cols (3 used), [4..131]=shift[0..127]

__device__ __forceinline__ float silu_f(float x) {
    return x / (1.0f + expf(-x));
}

// One MLP stage: out[8 rows x 64 cols] = act(in[8 rows, K] @ w[K x NC] + bias).
// 512 threads = 64 cols x KS=8 k-slices (wave-uniform). Each thread: 8 rows x
// 1 col; k-loop in chunks of 16 (16 independent scalar w loads per batch).
// ANTI-HOTSPOT ROTATIONS (new vs R9):
//   - colgroup rotation: cg = (blockIdx.y + g) % NCB, so concurrent blocks of
//     one rowgroup wavefront stream DIFFERENT weight column slices;
//   - k-phase rotation: the 16-row batch ring starts at phase (g mod P),
//     spreading same-slice blocks across 2-4 distinct k positions.
// Split-k partials reduced via LDS. COLMAP: only w cols {0..3} U [224,352).
template <int K, int NC, int OUTC, int OUTW, int NCB, bool EMB_IN, bool POST_SILU, bool COLMAP>
__global__ __launch_bounds__(512) void k_stage(
    const float* __restrict__ in,    // [M][K]  (unused if EMB_IN)
    const float* __restrict__ t,     // [M]     (EMB_IN only)
    const float* __restrict__ w,     // [K][NC]
    const float* __restrict__ bias,  // [NC]
    float* __restrict__ out)         // [M][OUTW]
{
    constexpr int KS = 8, KC = K / KS;   // K=256 -> 32, K=512 -> 64
    constexpr int C = 64;
    constexpr int P = KC / 16;           // k-phases: 2 or 4 (power of 2)

    __shared__ __align__(16) float s_in[8][K];        // 8 or 16 KB
    __shared__ __align__(16) float s_acc[KS][8][C];   // 16 KB

    int tid = threadIdx.x;
    int g = blockIdx.x;                  // rowgroup
    int row0 = g * 8;
    int cgr = blockIdx.y + g;            // rotated colgroup
    int cg = (NCB & (NCB - 1)) == 0 ? (cgr & (NCB - 1)) : (cgr % NCB);
    int col0 = cg * C;

    if constexpr (EMB_IN) {
        // timestep embedding into s_in: emb[j] = j<128 ? cos(t*f_j) : sin(t*f_{j-128})
        const float lm = 9.210340371976184f;   // ln(10000)
        for (int idx = tid; idx < 8 * K; idx += 512) {
            int r = idx / K, j = idx - r * K;
            int h = j & 127;
            float freq = expf(-lm * (float)h * (1.0f / 128.0f));
            float arg = t[row0 + r] * freq;
            s_in[r][j] = (j < 128) ? cosf(arg) : sinf(arg);
        }
    } else {
        for (int idx = tid; idx < 8 * (K / 4); idx += 512) {
            int r = idx / (K / 4), k4 = idx - r * (K / 4);
            *(float4*)&s_in[r][k4 * 4] =
                *(const float4*)(in + (size_t)(row0 + r) * K + k4 * 4);
        }
    }
    __syncthreads();

    int c  = tid & 63;
    int ks = tid >> 6;                     // wave-uniform k-slice (0..7)
    int oc = col0 + c;                     // output col
    int wcol;                              // col in w
    if constexpr (COLMAP) {
        int occ = (oc < OUTC) ? oc : (OUTC - 1);   // clamp (garbage, never stored)
        wcol = (occ < 4) ? occ : (220 + occ);      // {0..3} U [224,352)
    } else {
        wcol = (oc < NC) ? oc : (NC - 1);
    }
    const float* wp = w + wcol;

    float acc[8] = {0, 0, 0, 0, 0, 0, 0, 0};
    int kbeg = ks * KC;
    int p0 = g & (P - 1);                  // k-phase rotation

#pragma unroll 1
    for (int i = 0; i < P; ++i) {
        int k0 = kbeg + (((p0 + i) & (P - 1)) << 4);
        // 16 independent scalar w loads -> one batched waitcnt cluster
        float wv[16];
#pragma unroll
        for (int u = 0; u < 16; ++u) wv[u] = wp[(size_t)(k0 + u) * NC];
#pragma unroll
        for (int q = 0; q < 4; ++q) {
            float4 sa[8];
#pragma unroll
            for (int r = 0; r < 8; ++r) sa[r] = *(const float4*)&s_in[r][k0 + 4 * q];
#pragma unroll
            for (int u = 0; u < 4; ++u)
#pragma unroll
                for (int r = 0; r < 8; ++r)
                    acc[r] += ((const float*)&sa[r])[u] * wv[4 * q + u];
        }
    }

#pragma unroll
    for (int r = 0; r < 8; ++r) s_acc[ks][r][c] = acc[r];
    __syncthreads();

    // 512 outputs (8 rows x 64 cols), one per thread.
    {
        int r  = tid >> 6;
        int cc = tid & 63;
        int jo = col0 + cc;
        if (jo < OUTC) {
            int wc = COLMAP ? ((jo < 4) ? jo : (220 + jo)) : jo;
            float v = 0.f;
#pragma unroll
            for (int s = 0; s < KS; ++s) v += s_acc[s][r][cc];
            v += bias[wc];
            if (POST_SILU) v = silu_f(v);
            out[(size_t)(row0 + r) * OUTW + jo] = v;
        }
    }
}

// One wave (64 lanes) per node. Row = 480 f32 = 120 float4.
// f4 idx: 0..31 seg0 (LN, floats 0..127); 32..79 seg1 (128..319); 80..119 seg2 (320..479)
// mod row is compact MODW=132: [0..2] scales, [4+i] = shift[i] (i<128).
__global__ __launch_bounds__(256) void k_main(const float* __restrict__ x,
                                              const int* __restrict__ batch,
                                              const float* __restrict__ mod,
                                              float* __restrict__ out, int N) {
    int node = blockIdx.x * 4 + (threadIdx.x >> 6);
    if (node >= N) return;
    int lane = threadIdx.x & 63;

    const float4* rp = (const float4*)(x + (size_t)node * 480);
    float4 a = rp[lane];                         // f4 idx lane (0..63)
    float4 c = make_float4(0.f, 0.f, 0.f, 0.f);
    if (lane < 56) c = rp[64 + lane];            // f4 idx 64..119

    // hoisted mod gather: overlap gather latency with the shuffle reduce
    int b = batch[node];
    const float* mrow = mod + (size_t)b * MODW;
    float4 m4 = *(const float4*)mrow;            // scales 0..2 (+pad)
    float4 sh = make_float4(0.f, 0.f, 0.f, 0.f);
    if (lane < 32) sh = *(const float4*)(mrow + 4 + 4 * lane);   // shifts

    float s0 = 0.f, q0 = 0.f, q1 = 0.f, q2 = 0.f;
    float da = a.x * a.x + a.y * a.y + a.z * a.z + a.w * a.w;
    if (lane < 32) { s0 = a.x + a.y + a.z + a.w; q0 = da; }
    else           { q1 = da; }
    float dc = c.x * c.x + c.y * c.y + c.z * c.z + c.w * c.w;
    if (lane < 16)      q1 += dc;
    else if (lane < 56) q2 = dc;

#pragma unroll
    for (int m = 1; m < 64; m <<= 1) {
        s0 += __shfl_xor(s0, m, 64);
        q0 += __shfl_xor(q0, m, 64);
        q1 += __shfl_xor(q1, m, 64);
        q2 += __shfl_xor(q2, m, 64);
    }

    float mean = s0 * (1.0f / 128.0f);
    float var  = q0 * (1.0f / 128.0f) - mean * mean;
    float r0 = rsqrtf(var + EPS) * (1.0f + m4.x);
    float r1 = rsqrtf(q1 * (1.0f / 192.0f) + EPS) * (1.0f + m4.y);
    float r2 = rsqrtf(q2 * (1.0f / 160.0f) + EPS) * (1.0f + m4.z);

    float4* op = (float4*)(out + (size_t)node * 480);
    float4 o;
    if (lane < 32) {
        o.x = (a.x - mean) * r0 + sh.x;
        o.y = (a.y - mean) * r0 + sh.y;
        o.z = (a.z - mean) * r0 + sh.z;
        o.w = (a.w - mean) * r0 + sh.w;
    } else {
        o.x = a.x * r1; o.y = a.y * r1; o.z = a.z * r1; o.w = a.w * r1;
    }
    op[lane] = o;
    if (lane < 56) {
        float rr = (lane < 16) ? r1 : r2;
        float4 o2;
        o2.x = c.x * rr; o2.y = c.y * rr; o2.z = c.z * rr; o2.w = c.w * rr;
        op[64 + lane] = o2;
    }
}

extern "C" void kernel_launch(void* const* d_in, const int* in_sizes, int n_in,
                              void* d_out, int out_size, void* d_ws, size_t ws_size,
                              hipStream_t stream) {
    const float* node_input = (const float*)d_in[0];
    const float* t          = (const float*)d_in[1];
    const int*   batch      = (const int*)d_in[2];
    const float* w1         = (const float*)d_in[3];
    const float* b1         = (const float*)d_in[4];
    const float* w2         = (const float*)d_in[5];
    const float* b2         = (const float*)d_in[6];
    const float* wm         = (const float*)d_in[7];
    const float* bm         = (const float*)d_in[8];
    float* out = (float*)d_out;

    int N = in_sizes[0] / 480;   // 100000
    int B = in_sizes[1];         // 1024

    float* ws = (float*)d_ws;
    float* h1 = ws;                        // B*512: silu(emb@w1+b1)
    float* h2 = h1 + (size_t)B * 512;      // B*512: silu(h1@w2+b2)  (silu folded)
    float* mb = h2 + (size_t)B * 512;      // B*132: compact mod

    // stage 1: emb (in-kernel trig) @ w1 + b1, silu
    k_stage<256, 512, 512, 512, 8, true,  true,  false><<<dim3(B / 8, 8), 512, 0, stream>>>(
        nullptr, t, w1, b1, h1);
    // stage 2: h1 @ w2 + b2, trailing silu folded (next stage wants silu(t_emb))
    k_stage<512, 512, 512, 512, 8, false, true,  false><<<dim3(B / 8, 8), 512, 0, stream>>>(
        h1, nullptr, w2, b2, h2);
    // stage 3: h2 @ wm + bm, only cols {0..3} U [224,352) -> compact 132-col rows
    k_stage<512, 352, MODW, MODW, 3, false, false, true ><<<dim3(B / 8, 3), 512, 0, stream>>>(
        h2, nullptr, wm, bm, mb);

    k_main<<<(N + 3) / 4, 256, 0, stream>>>(node_input, batch, mb, out, N);
}